// Round 1
// baseline (823.437 us; speedup 1.0000x reference)
//
#include <hip/hip_runtime.h>
#include <hip/hip_bf16.h>

#define B_DIM 32
#define N_IN 1000000
#define N_OUT 500000

__global__ __launch_bounds__(256) void Encoder_24154896072769_kernel(
    const float* __restrict__ x,   // (B, N_IN)
    const float* __restrict__ w,   // (N_OUT, 3)
    const int*   __restrict__ idx, // (N_OUT, 3)
    float* __restrict__ out)       // (B, N_OUT)
{
    const int o = blockIdx.x * blockDim.x + threadIdx.x;
    if (o >= N_OUT) return;

    const int base = 3 * o;
    const int i0 = idx[base + 0];
    const int i1 = idx[base + 1];
    const int i2 = idx[base + 2];
    const float w0 = w[base + 0];
    const float w1 = w[base + 1];
    const float w2 = w[base + 2];

#pragma unroll 4
    for (int b = 0; b < B_DIM; ++b) {
        const float* __restrict__ xr = x + (size_t)b * N_IN;
        float acc = w0 * xr[i0];
        acc = fmaf(w1, xr[i1], acc);
        acc = fmaf(w2, xr[i2], acc);
        out[(size_t)b * N_OUT + o] = acc;
    }
}

extern "C" void kernel_launch(void* const* d_in, const int* in_sizes, int n_in,
                              void* d_out, int out_size, void* d_ws, size_t ws_size,
                              hipStream_t stream) {
    const float* x   = (const float*)d_in[0];
    const float* w   = (const float*)d_in[1];
    const int*   idx = (const int*)d_in[2];
    float* out = (float*)d_out;

    const int threads = 256;
    const int blocks = (N_OUT + threads - 1) / threads;
    Encoder_24154896072769_kernel<<<blocks, threads, 0, stream>>>(x, w, idx, out);
}

// Round 2
// 284.172 us; speedup vs baseline: 2.8977x; 2.8977x over previous
//
#include <hip/hip_runtime.h>
#include <hip/hip_bf16.h>

#define B_DIM 32
#define N_IN 1000000
#define N_OUT 500000

// ---------- Kernel 1: transpose x (B, N_IN) -> xT (N_IN, B) ----------
// Tile: 32 rows (all of B) x 64 columns of i, staged through LDS.
// Pad leading dim to 65 so the write-phase read (lane -> bi) is conflict-free.
__global__ __launch_bounds__(256) void transpose_kernel(
    const float* __restrict__ x, float* __restrict__ xT)
{
    __shared__ float tile[32][65];
    const int t = threadIdx.x;
    const int i0 = blockIdx.x * 64;

#pragma unroll
    for (int it = 0; it < 8; ++it) {
        const int e  = it * 256 + t;
        const int bi = e >> 6;      // 0..31
        const int ii = e & 63;      // 0..63
        // wave lanes sweep ii -> fully coalesced 256B reads per row
        tile[bi][ii] = x[(size_t)bi * N_IN + (i0 + ii)];
    }
    __syncthreads();
#pragma unroll
    for (int it = 0; it < 8; ++it) {
        const int e  = it * 256 + t;
        const int ii = e >> 5;      // 0..63
        const int bi = e & 31;      // 0..31
        // consecutive lanes -> consecutive (ii*32 + bi) -> coalesced stores
        xT[(size_t)(i0 + ii) * B_DIM + bi] = tile[bi][ii];
    }
}

// ---------- Kernel 2: gather from xT with full-line utilization ----------
// One thread per output column o. Each of its 3 indices reads a contiguous
// 128B chunk (all 32 batch values) as 8x float4.
__global__ __launch_bounds__(256) void gather_kernel(
    const float* __restrict__ xT,  // (N_IN, B)
    const float* __restrict__ w,   // (N_OUT, 3)
    const int*   __restrict__ idx, // (N_OUT, 3)
    float* __restrict__ out)       // (B, N_OUT)
{
    const int o = blockIdx.x * blockDim.x + threadIdx.x;
    if (o >= N_OUT) return;

    const int base = 3 * o;
    const int i0 = idx[base + 0];
    const int i1 = idx[base + 1];
    const int i2 = idx[base + 2];
    const float w0 = w[base + 0];
    const float w1 = w[base + 1];
    const float w2 = w[base + 2];

    float acc[B_DIM];
#pragma unroll
    for (int b = 0; b < B_DIM; ++b) acc[b] = 0.0f;

    const float4* __restrict__ p0 = (const float4*)(xT + (size_t)i0 * B_DIM);
    const float4* __restrict__ p1 = (const float4*)(xT + (size_t)i1 * B_DIM);
    const float4* __restrict__ p2 = (const float4*)(xT + (size_t)i2 * B_DIM);

#pragma unroll
    for (int q = 0; q < 8; ++q) {
        const float4 v0 = p0[q];
        const float4 v1 = p1[q];
        const float4 v2 = p2[q];
        acc[q * 4 + 0] = fmaf(w0, v0.x, fmaf(w1, v1.x, fmaf(w2, v2.x, acc[q * 4 + 0])));
        acc[q * 4 + 1] = fmaf(w0, v0.y, fmaf(w1, v1.y, fmaf(w2, v2.y, acc[q * 4 + 1])));
        acc[q * 4 + 2] = fmaf(w0, v0.z, fmaf(w1, v1.z, fmaf(w2, v2.z, acc[q * 4 + 2])));
        acc[q * 4 + 3] = fmaf(w0, v0.w, fmaf(w1, v1.w, fmaf(w2, v2.w, acc[q * 4 + 3])));
    }

#pragma unroll
    for (int b = 0; b < B_DIM; ++b) {
        // consecutive o across the wave -> coalesced per-b store
        out[(size_t)b * N_OUT + o] = acc[b];
    }
}

// ---------- Fallback (ws too small): direct gather, round-1 kernel ----------
__global__ __launch_bounds__(256) void direct_kernel(
    const float* __restrict__ x,
    const float* __restrict__ w,
    const int*   __restrict__ idx,
    float* __restrict__ out)
{
    const int o = blockIdx.x * blockDim.x + threadIdx.x;
    if (o >= N_OUT) return;

    const int base = 3 * o;
    const int i0 = idx[base + 0];
    const int i1 = idx[base + 1];
    const int i2 = idx[base + 2];
    const float w0 = w[base + 0];
    const float w1 = w[base + 1];
    const float w2 = w[base + 2];

#pragma unroll 4
    for (int b = 0; b < B_DIM; ++b) {
        const float* __restrict__ xr = x + (size_t)b * N_IN;
        float acc = w0 * xr[i0];
        acc = fmaf(w1, xr[i1], acc);
        acc = fmaf(w2, xr[i2], acc);
        out[(size_t)b * N_OUT + o] = acc;
    }
}

extern "C" void kernel_launch(void* const* d_in, const int* in_sizes, int n_in,
                              void* d_out, int out_size, void* d_ws, size_t ws_size,
                              hipStream_t stream) {
    const float* x   = (const float*)d_in[0];
    const float* w   = (const float*)d_in[1];
    const int*   idx = (const int*)d_in[2];
    float* out = (float*)d_out;

    const size_t xt_bytes = (size_t)N_IN * B_DIM * sizeof(float); // 128 MB

    if (ws_size >= xt_bytes) {
        float* xT = (float*)d_ws;
        transpose_kernel<<<N_IN / 64, 256, 0, stream>>>(x, xT);
        const int blocks = (N_OUT + 255) / 256;
        gather_kernel<<<blocks, 256, 0, stream>>>(xT, w, idx, out);
    } else {
        const int blocks = (N_OUT + 255) / 256;
        direct_kernel<<<blocks, 256, 0, stream>>>(x, w, idx, out);
    }
}

// Round 3
// 266.702 us; speedup vs baseline: 3.0875x; 1.0655x over previous
//
#include <hip/hip_runtime.h>
#include <hip/hip_bf16.h>

#define B_DIM 32
#define N_IN 1000000
#define N_OUT 500000

__device__ __forceinline__ unsigned int f32_to_bf16_rne(float f) {
    unsigned int u = __float_as_uint(f);
    unsigned int rounding = 0x7fffu + ((u >> 16) & 1u);
    return (u + rounding) >> 16;   // low 16 bits = bf16
}

// ---------- Kernel 1: transpose+downconvert x (B,N_IN) f32 -> xT (N_IN,B) bf16 ----
// Tile: all 32 b x 64 i-columns. float4 global loads, scalar LDS writes into
// transposed tile (pad 33 -> 2-way bank aliasing, free), 16B packed bf16 stores.
__global__ __launch_bounds__(256) void transpose_bf16_kernel(
    const float* __restrict__ x, unsigned short* __restrict__ xT)
{
    __shared__ float tile_t[64][33];   // [ii][bi]
    const int t  = threadIdx.x;
    const int i0 = blockIdx.x * 64;

    // Load phase: 512 float4 per block, 2 per thread.
#pragma unroll
    for (int it = 0; it < 2; ++it) {
        const int q  = it * 256 + t;
        const int bi = q >> 4;        // 0..31
        const int qi = q & 15;        // 0..15 (float4 index within row)
        const float4 v = *(const float4*)(x + (size_t)bi * N_IN + i0 + qi * 4);
        tile_t[qi * 4 + 0][bi] = v.x;
        tile_t[qi * 4 + 1][bi] = v.y;
        tile_t[qi * 4 + 2][bi] = v.z;
        tile_t[qi * 4 + 3][bi] = v.w;
    }
    __syncthreads();

    // Store phase: 256 chunks of 16B (8 bf16) — one per thread.
    const int ii = t >> 2;            // 0..63
    const int j  = t & 3;             // 0..3 (which 8-b group)
    uint4 pk;
    {
        const float f0 = tile_t[ii][j * 8 + 0];
        const float f1 = tile_t[ii][j * 8 + 1];
        const float f2 = tile_t[ii][j * 8 + 2];
        const float f3 = tile_t[ii][j * 8 + 3];
        const float f4 = tile_t[ii][j * 8 + 4];
        const float f5 = tile_t[ii][j * 8 + 5];
        const float f6 = tile_t[ii][j * 8 + 6];
        const float f7 = tile_t[ii][j * 8 + 7];
        pk.x = f32_to_bf16_rne(f0) | (f32_to_bf16_rne(f1) << 16);
        pk.y = f32_to_bf16_rne(f2) | (f32_to_bf16_rne(f3) << 16);
        pk.z = f32_to_bf16_rne(f4) | (f32_to_bf16_rne(f5) << 16);
        pk.w = f32_to_bf16_rne(f6) | (f32_to_bf16_rne(f7) << 16);
    }
    // consecutive t -> contiguous 16B chunks -> 1KB per wave store
    *(uint4*)((char*)xT + (size_t)(i0 + ii) * 64 + j * 16) = pk;
}

// ---------- Kernel 2: gather from bf16 xT — one 64B line per index ----------
__global__ __launch_bounds__(256) void gather_bf16_kernel(
    const unsigned short* __restrict__ xT,  // (N_IN, 32) bf16
    const float* __restrict__ w,            // (N_OUT, 3)
    const int*   __restrict__ idx,          // (N_OUT, 3)
    float* __restrict__ out)                // (B, N_OUT)
{
    const int o = blockIdx.x * blockDim.x + threadIdx.x;
    if (o >= N_OUT) return;

    const int base = 3 * o;
    const int i0 = idx[base + 0];
    const int i1 = idx[base + 1];
    const int i2 = idx[base + 2];
    const float w0 = w[base + 0];
    const float w1 = w[base + 1];
    const float w2 = w[base + 2];

    const uint4* __restrict__ p0 = (const uint4*)(xT + (size_t)i0 * B_DIM);
    const uint4* __restrict__ p1 = (const uint4*)(xT + (size_t)i1 * B_DIM);
    const uint4* __restrict__ p2 = (const uint4*)(xT + (size_t)i2 * B_DIM);

    float acc[B_DIM];
#pragma unroll
    for (int b = 0; b < B_DIM; ++b) acc[b] = 0.0f;

#pragma unroll
    for (int q = 0; q < 4; ++q) {   // 4 x uint4 = 32 bf16 per index
        const uint4 v0 = p0[q];
        const uint4 v1 = p1[q];
        const uint4 v2 = p2[q];
        const unsigned int u0[4] = {v0.x, v0.y, v0.z, v0.w};
        const unsigned int u1[4] = {v1.x, v1.y, v1.z, v1.w};
        const unsigned int u2[4] = {v2.x, v2.y, v2.z, v2.w};
#pragma unroll
        for (int m = 0; m < 4; ++m) {
            const int b = q * 8 + m * 2;
            float a = acc[b], c = acc[b + 1];
            a = fmaf(w0, __uint_as_float(u0[m] << 16), a);
            c = fmaf(w0, __uint_as_float(u0[m] & 0xffff0000u), c);
            a = fmaf(w1, __uint_as_float(u1[m] << 16), a);
            c = fmaf(w1, __uint_as_float(u1[m] & 0xffff0000u), c);
            a = fmaf(w2, __uint_as_float(u2[m] << 16), a);
            c = fmaf(w2, __uint_as_float(u2[m] & 0xffff0000u), c);
            acc[b] = a; acc[b + 1] = c;
        }
    }

#pragma unroll
    for (int b = 0; b < B_DIM; ++b) {
        out[(size_t)b * N_OUT + o] = acc[b];   // coalesced per-b
    }
}

// ---------- Fallback (ws too small): direct fp32 gather ----------
__global__ __launch_bounds__(256) void direct_kernel(
    const float* __restrict__ x,
    const float* __restrict__ w,
    const int*   __restrict__ idx,
    float* __restrict__ out)
{
    const int o = blockIdx.x * blockDim.x + threadIdx.x;
    if (o >= N_OUT) return;
    const int base = 3 * o;
    const int i0 = idx[base + 0], i1 = idx[base + 1], i2 = idx[base + 2];
    const float w0 = w[base + 0], w1 = w[base + 1], w2 = w[base + 2];
#pragma unroll 4
    for (int b = 0; b < B_DIM; ++b) {
        const float* __restrict__ xr = x + (size_t)b * N_IN;
        float acc = w0 * xr[i0];
        acc = fmaf(w1, xr[i1], acc);
        acc = fmaf(w2, xr[i2], acc);
        out[(size_t)b * N_OUT + o] = acc;
    }
}

extern "C" void kernel_launch(void* const* d_in, const int* in_sizes, int n_in,
                              void* d_out, int out_size, void* d_ws, size_t ws_size,
                              hipStream_t stream) {
    const float* x   = (const float*)d_in[0];
    const float* w   = (const float*)d_in[1];
    const int*   idx = (const int*)d_in[2];
    float* out = (float*)d_out;

    const size_t xt_bytes = (size_t)N_IN * B_DIM * sizeof(unsigned short); // 64 MB

    if (ws_size >= xt_bytes) {
        unsigned short* xT = (unsigned short*)d_ws;
        transpose_bf16_kernel<<<N_IN / 64, 256, 0, stream>>>(x, xT);
        const int blocks = (N_OUT + 255) / 256;
        gather_bf16_kernel<<<blocks, 256, 0, stream>>>(xT, w, idx, out);
    } else {
        const int blocks = (N_OUT + 255) / 256;
        direct_kernel<<<blocks, 256, 0, stream>>>(x, w, idx, out);
    }
}

// Round 5
// 254.250 us; speedup vs baseline: 3.2387x; 1.0490x over previous
//
#include <hip/hip_runtime.h>
#include <hip/hip_bf16.h>

#define B_DIM 32
#define N_IN 1000000
#define N_OUT 500000

typedef float  nfloat4 __attribute__((ext_vector_type(4)));

__device__ __forceinline__ unsigned int f32_to_bf16_rne(float f) {
    unsigned int u = __float_as_uint(f);
    unsigned int rounding = 0x7fffu + ((u >> 16) & 1u);
    return (u + rounding) >> 16;   // low 16 bits = bf16
}

// ---------- Kernel 1: transpose+downconvert x (B,N_IN) f32 -> xT (N_IN,B) bf16 ----
// Tile: 64 i-columns x all 32 b. Convert+pack b-pairs BEFORE LDS:
//   load 2 consecutive b-rows as 16B nontemporal (coalesced), pack bf16{b,b+1}
//   into uint, 4x ds_write_b32, then 1x ds_read_b128 + 1x 16B global store.
__global__ __launch_bounds__(256) void transpose_bf16_kernel(
    const float* __restrict__ x, unsigned short* __restrict__ xT)
{
    __shared__ unsigned int tile[64][17];   // [ii][b-pair], pad 17 -> <=2-way banks
    const int t  = threadIdx.x;
    const int i0 = blockIdx.x * 64;

    const int qi = t & 15;       // float4-column 0..15 (fast -> coalesced)
    const int p  = t >> 4;       // b-pair 0..15

    const float* r0 = x + (size_t)(2 * p)     * N_IN + i0 + qi * 4;
    const float* r1 = x + (size_t)(2 * p + 1) * N_IN + i0 + qi * 4;
    const nfloat4 va = __builtin_nontemporal_load((const nfloat4*)r0);
    const nfloat4 vb = __builtin_nontemporal_load((const nfloat4*)r1);

    tile[qi * 4 + 0][p] = f32_to_bf16_rne(va.x) | (f32_to_bf16_rne(vb.x) << 16);
    tile[qi * 4 + 1][p] = f32_to_bf16_rne(va.y) | (f32_to_bf16_rne(vb.y) << 16);
    tile[qi * 4 + 2][p] = f32_to_bf16_rne(va.z) | (f32_to_bf16_rne(vb.z) << 16);
    tile[qi * 4 + 3][p] = f32_to_bf16_rne(va.w) | (f32_to_bf16_rne(vb.w) << 16);
    __syncthreads();

    // Store phase: one 16B chunk (8 bf16 = 4 packed pairs) per thread.
    const int ii = t >> 2;       // 0..63
    const int g  = t & 3;        // 0..3
    uint4 pk;
    pk.x = tile[ii][g * 4 + 0];
    pk.y = tile[ii][g * 4 + 1];
    pk.z = tile[ii][g * 4 + 2];
    pk.w = tile[ii][g * 4 + 3];
    // consecutive t -> contiguous addresses -> fully coalesced 1KB/wave
    *(uint4*)((char*)xT + (size_t)(i0 + ii) * 64 + g * 16) = pk;
}

// ---------- Kernel 2: gather from bf16 xT — one 64B line per index ----------
__global__ __launch_bounds__(256) void gather_bf16_kernel(
    const unsigned short* __restrict__ xT,  // (N_IN, 32) bf16
    const float* __restrict__ w,            // (N_OUT, 3)
    const int*   __restrict__ idx,          // (N_OUT, 3)
    float* __restrict__ out)                // (B, N_OUT)
{
    const int o = blockIdx.x * blockDim.x + threadIdx.x;
    if (o >= N_OUT) return;

    const int base = 3 * o;
    const int i0 = idx[base + 0];
    const int i1 = idx[base + 1];
    const int i2 = idx[base + 2];
    const float w0 = w[base + 0];
    const float w1 = w[base + 1];
    const float w2 = w[base + 2];

    const uint4* __restrict__ p0 = (const uint4*)(xT + (size_t)i0 * B_DIM);
    const uint4* __restrict__ p1 = (const uint4*)(xT + (size_t)i1 * B_DIM);
    const uint4* __restrict__ p2 = (const uint4*)(xT + (size_t)i2 * B_DIM);

    // Issue all 12 independent 16B loads up-front (max MLP).
    uint4 v0[4], v1[4], v2[4];
#pragma unroll
    for (int q = 0; q < 4; ++q) v0[q] = p0[q];
#pragma unroll
    for (int q = 0; q < 4; ++q) v1[q] = p1[q];
#pragma unroll
    for (int q = 0; q < 4; ++q) v2[q] = p2[q];

    float acc[B_DIM];
#pragma unroll
    for (int b = 0; b < B_DIM; ++b) acc[b] = 0.0f;

#pragma unroll
    for (int q = 0; q < 4; ++q) {
        const unsigned int u0[4] = {v0[q].x, v0[q].y, v0[q].z, v0[q].w};
        const unsigned int u1[4] = {v1[q].x, v1[q].y, v1[q].z, v1[q].w};
        const unsigned int u2[4] = {v2[q].x, v2[q].y, v2[q].z, v2[q].w};
#pragma unroll
        for (int m = 0; m < 4; ++m) {
            const int b = q * 8 + m * 2;
            float a = acc[b], c = acc[b + 1];
            a = fmaf(w0, __uint_as_float(u0[m] << 16), a);
            c = fmaf(w0, __uint_as_float(u0[m] & 0xffff0000u), c);
            a = fmaf(w1, __uint_as_float(u1[m] << 16), a);
            c = fmaf(w1, __uint_as_float(u1[m] & 0xffff0000u), c);
            a = fmaf(w2, __uint_as_float(u2[m] << 16), a);
            c = fmaf(w2, __uint_as_float(u2[m] & 0xffff0000u), c);
            acc[b] = a; acc[b + 1] = c;
        }
    }

#pragma unroll
    for (int b = 0; b < B_DIM; ++b) {
        // never re-read -> nontemporal; keeps xT resident in L2/L3
        __builtin_nontemporal_store(acc[b], &out[(size_t)b * N_OUT + o]);
    }
}

// ---------- Fallback (ws too small): direct fp32 gather ----------
__global__ __launch_bounds__(256) void direct_kernel(
    const float* __restrict__ x,
    const float* __restrict__ w,
    const int*   __restrict__ idx,
    float* __restrict__ out)
{
    const int o = blockIdx.x * blockDim.x + threadIdx.x;
    if (o >= N_OUT) return;
    const int base = 3 * o;
    const int i0 = idx[base + 0], i1 = idx[base + 1], i2 = idx[base + 2];
    const float w0 = w[base + 0], w1 = w[base + 1], w2 = w[base + 2];
#pragma unroll 4
    for (int b = 0; b < B_DIM; ++b) {
        const float* __restrict__ xr = x + (size_t)b * N_IN;
        float acc = w0 * xr[i0];
        acc = fmaf(w1, xr[i1], acc);
        acc = fmaf(w2, xr[i2], acc);
        out[(size_t)b * N_OUT + o] = acc;
    }
}

extern "C" void kernel_launch(void* const* d_in, const int* in_sizes, int n_in,
                              void* d_out, int out_size, void* d_ws, size_t ws_size,
                              hipStream_t stream) {
    const float* x   = (const float*)d_in[0];
    const float* w   = (const float*)d_in[1];
    const int*   idx = (const int*)d_in[2];
    float* out = (float*)d_out;

    const size_t xt_bytes = (size_t)N_IN * B_DIM * sizeof(unsigned short); // 64 MB

    if (ws_size >= xt_bytes) {
        unsigned short* xT = (unsigned short*)d_ws;
        transpose_bf16_kernel<<<N_IN / 64, 256, 0, stream>>>(x, xT);
        const int blocks = (N_OUT + 255) / 256;
        gather_bf16_kernel<<<blocks, 256, 0, stream>>>(xT, w, idx, out);
    } else {
        const int blocks = (N_OUT + 255) / 256;
        direct_kernel<<<blocks, 256, 0, stream>>>(x, w, idx, out);
    }
}

// Round 6
// 248.265 us; speedup vs baseline: 3.3168x; 1.0241x over previous
//
#include <hip/hip_runtime.h>
#include <hip/hip_bf16.h>

#define B_DIM 32
#define N_IN 1000000
#define N_OUT 500000

typedef float nfloat4 __attribute__((ext_vector_type(4)));

__device__ __forceinline__ unsigned int f32_to_bf16_rne(float f) {
    unsigned int u = __float_as_uint(f);
    unsigned int rounding = 0x7fffu + ((u >> 16) & 1u);
    return (u + rounding) >> 16;   // low 16 bits = bf16
}

// ---------- Kernel 1: transpose+downconvert x (B,N_IN) f32 -> xT (N_IN,B) bf16 ----
__global__ __launch_bounds__(256) void transpose_bf16_kernel(
    const float* __restrict__ x, unsigned short* __restrict__ xT)
{
    __shared__ unsigned int tile[64][17];   // [ii][b-pair], pad 17 -> <=2-way banks
    const int t  = threadIdx.x;
    const int i0 = blockIdx.x * 64;

    const int qi = t & 15;       // float4-column 0..15 (fast -> coalesced)
    const int p  = t >> 4;       // b-pair 0..15

    const float* r0 = x + (size_t)(2 * p)     * N_IN + i0 + qi * 4;
    const float* r1 = x + (size_t)(2 * p + 1) * N_IN + i0 + qi * 4;
    const nfloat4 va = __builtin_nontemporal_load((const nfloat4*)r0);
    const nfloat4 vb = __builtin_nontemporal_load((const nfloat4*)r1);

    tile[qi * 4 + 0][p] = f32_to_bf16_rne(va.x) | (f32_to_bf16_rne(vb.x) << 16);
    tile[qi * 4 + 1][p] = f32_to_bf16_rne(va.y) | (f32_to_bf16_rne(vb.y) << 16);
    tile[qi * 4 + 2][p] = f32_to_bf16_rne(va.z) | (f32_to_bf16_rne(vb.z) << 16);
    tile[qi * 4 + 3][p] = f32_to_bf16_rne(va.w) | (f32_to_bf16_rne(vb.w) << 16);
    __syncthreads();

    const int ii = t >> 2;       // 0..63
    const int g  = t & 3;        // 0..3
    uint4 pk;
    pk.x = tile[ii][g * 4 + 0];
    pk.y = tile[ii][g * 4 + 1];
    pk.z = tile[ii][g * 4 + 2];
    pk.w = tile[ii][g * 4 + 3];
    *(uint4*)((char*)xT + (size_t)(i0 + ii) * 64 + g * 16) = pk;
}

// ---------- Kernel 2: cooperative gather — 4 lanes share one 64B line ----------
// Group of 4 consecutive lanes handles one o; lane l loads 16B chunk l of each
// indexed row -> one merged 64B transaction per line (3 per o, the minimum).
__global__ __launch_bounds__(256) void gather_bf16_v2_kernel(
    const unsigned short* __restrict__ xT,  // (N_IN, 32) bf16
    const float* __restrict__ w,            // (N_OUT, 3)
    const int*   __restrict__ idx,          // (N_OUT, 3)
    float* __restrict__ out)                // (B, N_OUT)
{
    const int t = threadIdx.x;
    const int g = t >> 2;                   // group 0..63
    const int l = t & 3;                    // 16B chunk within line
    const int o = blockIdx.x * 64 + g;
    if (o >= N_OUT) return;

    const int base = 3 * o;
    // read-once streams: nontemporal, same-address across the 4 group lanes
    const int   i0 = __builtin_nontemporal_load(idx + base + 0);
    const int   i1 = __builtin_nontemporal_load(idx + base + 1);
    const int   i2 = __builtin_nontemporal_load(idx + base + 2);
    const float w0 = __builtin_nontemporal_load(w + base + 0);
    const float w1 = __builtin_nontemporal_load(w + base + 1);
    const float w2 = __builtin_nontemporal_load(w + base + 2);

    // lane l's 16B chunk of each 64B row: b = 8l .. 8l+7
    const uint4 v0 = *(const uint4*)(xT + (size_t)i0 * B_DIM + l * 8);
    const uint4 v1 = *(const uint4*)(xT + (size_t)i1 * B_DIM + l * 8);
    const uint4 v2 = *(const uint4*)(xT + (size_t)i2 * B_DIM + l * 8);

    float acc[8];
#pragma unroll
    for (int j = 0; j < 8; ++j) acc[j] = 0.0f;

    const unsigned int u0[4] = {v0.x, v0.y, v0.z, v0.w};
    const unsigned int u1[4] = {v1.x, v1.y, v1.z, v1.w};
    const unsigned int u2[4] = {v2.x, v2.y, v2.z, v2.w};
#pragma unroll
    for (int m = 0; m < 4; ++m) {
        float a = acc[2 * m], c = acc[2 * m + 1];
        a = fmaf(w0, __uint_as_float(u0[m] << 16), a);
        c = fmaf(w0, __uint_as_float(u0[m] & 0xffff0000u), c);
        a = fmaf(w1, __uint_as_float(u1[m] << 16), a);
        c = fmaf(w1, __uint_as_float(u1[m] & 0xffff0000u), c);
        a = fmaf(w2, __uint_as_float(u2[m] << 16), a);
        c = fmaf(w2, __uint_as_float(u2[m] & 0xffff0000u), c);
        acc[2 * m] = a; acc[2 * m + 1] = c;
    }

    // lane l owns b = 8l..8l+7; per store inst: 4 segments x 64B, coalesced
    float* obase = out + (size_t)(8 * l) * N_OUT + o;
#pragma unroll
    for (int j = 0; j < 8; ++j) {
        __builtin_nontemporal_store(acc[j], obase + (size_t)j * N_OUT);
    }
}

// ---------- Fallback (ws too small): direct fp32 gather ----------
__global__ __launch_bounds__(256) void direct_kernel(
    const float* __restrict__ x,
    const float* __restrict__ w,
    const int*   __restrict__ idx,
    float* __restrict__ out)
{
    const int o = blockIdx.x * blockDim.x + threadIdx.x;
    if (o >= N_OUT) return;
    const int base = 3 * o;
    const int i0 = idx[base + 0], i1 = idx[base + 1], i2 = idx[base + 2];
    const float w0 = w[base + 0], w1 = w[base + 1], w2 = w[base + 2];
#pragma unroll 4
    for (int b = 0; b < B_DIM; ++b) {
        const float* __restrict__ xr = x + (size_t)b * N_IN;
        float acc = w0 * xr[i0];
        acc = fmaf(w1, xr[i1], acc);
        acc = fmaf(w2, xr[i2], acc);
        out[(size_t)b * N_OUT + o] = acc;
    }
}

extern "C" void kernel_launch(void* const* d_in, const int* in_sizes, int n_in,
                              void* d_out, int out_size, void* d_ws, size_t ws_size,
                              hipStream_t stream) {
    const float* x   = (const float*)d_in[0];
    const float* w   = (const float*)d_in[1];
    const int*   idx = (const int*)d_in[2];
    float* out = (float*)d_out;

    const size_t xt_bytes = (size_t)N_IN * B_DIM * sizeof(unsigned short); // 64 MB

    if (ws_size >= xt_bytes) {
        unsigned short* xT = (unsigned short*)d_ws;
        transpose_bf16_kernel<<<N_IN / 64, 256, 0, stream>>>(x, xT);
        const int blocks = (N_OUT + 63) / 64;   // 64 o's per block (4 lanes/o)
        gather_bf16_v2_kernel<<<blocks, 256, 0, stream>>>(xT, w, idx, out);
    } else {
        const int blocks = (N_OUT + 255) / 256;
        direct_kernel<<<blocks, 256, 0, stream>>>(x, w, idx, out);
    }
}